// Round 1
// baseline (148.106 us; speedup 1.0000x reference)
//
#include <hip/hip_runtime.h>
#include <float.h>

// QKV attention, qkv [2,3072,2048] f32, mask [2,1,2048] i32, out [2,1024,2048] f32.
// Prep: f32->bf16; Q -> [bh][t][c] (pre-scaled 1/8*log2e); K,V -> FRAG-MAJOR:
// per (head, s-tile, frag) a 64-lane x 16B contiguous block == one coalesced
// 1KB wave load that lands directly in MFMA A/B layout.
// Main: flash loop with LDS-staged K/V (double-buffered via global_load_lds,
// one barrier/iter). Previously every wave loaded the same 16KB K/V tile from
// L1/L2 each iter (128KB/CU-iter, the measured 4600cyc/iter floor); now the
// tile is staged ONCE per block (16KB/CU-iter) and consumed via conflict-free
// ds_read_b128. Fixed-max exp2 softmax, mask folded into MFMA C-init bias,
// P via swizzled wave-private LDS round-trip.

typedef __attribute__((ext_vector_type(8))) short bf16x8;
typedef __attribute__((ext_vector_type(4))) float f32x4;

#define TSEQ 2048
#define QT_OFF 0L
#define KF_OFF 4194304L
#define VF_OFF 8388608L

#if __has_builtin(__builtin_amdgcn_exp2f)
#define EXPFN(x) __builtin_amdgcn_exp2f(x)
#define SM_SCALE (0.125f * 1.44269504088896f)
#else
#define EXPFN(x) __expf(x)
#define SM_SCALE 0.125f
#endif

// async global->LDS, 16B per lane; LDS dest is wave-uniform base + lane*16
#define GLOAD16(g, l) __builtin_amdgcn_global_load_lds( \
    (const __attribute__((address_space(1))) void*)(g), \
    (__attribute__((address_space(3))) void*)(l), 16, 0, 0)

__device__ inline short f2bf(float x) {
    union { float f; unsigned u; } un; un.f = x;
    unsigned r = un.u + 0x7fffu + ((un.u >> 16) & 1u);  // RNE
    return (short)(r >> 16);
}

// pack two nonneg floats to bf16 pair, round-half-up: 1 add each + 1 perm
__device__ inline unsigned pkbf(float a, float b) {
    unsigned au = __float_as_uint(a) + 0x8000u;
    unsigned bu = __float_as_uint(b) + 0x8000u;
    return __builtin_amdgcn_perm(bu, au, 0x07060302u);  // [a_hi16 | b_hi16<<16]
}

// ---------------- pre-pass: convert + reorder ----------------
__global__ __launch_bounds__(256) void prep_kernel(
    const float* __restrict__ qkv, short* __restrict__ ws)
{
    const int tid = threadIdx.x;
    const int job = blockIdx.x;
    if (job < 2048) {
        __shared__ float Ls[64 * 65];   // [c][t]
        const int which = job & 1;      // 0=Q 1=K
        const int rest  = job >> 1;
        const int bh = rest & 31, tt = rest >> 5;
        const int b = bh >> 4, h = bh & 15;
        const float* src = qkv + (long)b * 6291456 + ((long)(which * 1024 + h * 64)) * TSEQ + tt * 64;
        #pragma unroll
        for (int ch = 0; ch < 4; ++ch) {
            int idx = tid + ch * 256;
            int c = idx >> 4, tch = idx & 15;
            float4 v = *(const float4*)(src + (long)c * TSEQ + tch * 4);
            float* L = &Ls[c * 65 + tch * 4];
            L[0] = v.x; L[1] = v.y; L[2] = v.z; L[3] = v.w;
        }
        __syncthreads();
        if (which == 0) {
            // Q -> [t][c], scaled
            short* dst = ws + QT_OFF + ((long)bh * TSEQ + tt * 64) * 64;
            #pragma unroll
            for (int ch = 0; ch < 2; ++ch) {
                int idx = tid + ch * 256;
                int t = idx >> 3, cch = idx & 7;
                bf16x8 o;
                #pragma unroll
                for (int j = 0; j < 8; ++j)
                    o[j] = f2bf(Ls[(cch * 8 + j) * 65 + t] * SM_SCALE);
                *(bf16x8*)(dst + (long)t * 64 + cch * 8) = o;
            }
        } else {
            // K -> frag-major: unit (f=ns*2+hf, lane) = K[s=tt*64+ns*16+l15][c=hf*32+q*8+j]
            short* dst = ws + KF_OFF + (long)(bh * 32 + tt) * 4096;
            #pragma unroll
            for (int ch = 0; ch < 2; ++ch) {
                int u = tid + ch * 256;             // 0..511
                int f = u >> 6, lane = u & 63;
                int q = lane >> 4, l15 = lane & 15;
                int hf = f & 1, ns = f >> 1;
                bf16x8 o;
                #pragma unroll
                for (int j = 0; j < 8; ++j)
                    o[j] = f2bf(Ls[(hf * 32 + q * 8 + j) * 65 + ns * 16 + l15]);
                *(bf16x8*)(dst + f * 512 + lane * 8) = o;
            }
        }
    } else {
        // V -> frag-major: unit (f=nc*2+hf, lane) = V[c=nc*16+l15][s=it*64+hf*32+q*8+j]
        const int v = job - 2048;               // 0..1023
        const int head = v >> 5, it = v & 31;
        const int b = head >> 4, h = head & 15;
        short* dst = ws + VF_OFF + (long)(head * 32 + it) * 4096;
        #pragma unroll
        for (int ch = 0; ch < 2; ++ch) {
            int u = tid * 2 + ch;               // thread writes 32B contiguous
            int f = u >> 6, lane = u & 63;
            int q = lane >> 4, l15 = lane & 15;
            int hf = f & 1, nc = f >> 1;
            const float* src = qkv + (long)b * 6291456
                + ((long)(2048 + h * 64 + nc * 16 + l15)) * TSEQ
                + it * 64 + hf * 32 + q * 8;
            float4 a  = *(const float4*)src;
            float4 c4 = *(const float4*)(src + 4);
            bf16x8 o;
            o[0] = f2bf(a.x);  o[1] = f2bf(a.y);  o[2] = f2bf(a.z);  o[3] = f2bf(a.w);
            o[4] = f2bf(c4.x); o[5] = f2bf(c4.y); o[6] = f2bf(c4.z); o[7] = f2bf(c4.w);
            *(bf16x8*)(dst + f * 512 + lane * 8) = o;
        }
    }
}

// ---------------- main attention (LDS-staged K/V, 1 barrier/iter) ----------------
__global__ __launch_bounds__(512, 2) void attn_kernel(
    const short* __restrict__ ws, const int* __restrict__ mask,
    float* __restrict__ out)
{
    __shared__ __align__(16) char smem[73728];
    // [0,32768): K/V stage double-buffer: buf b at b*16384 (K 8KB | V 8KB)
    short* Ps  = (short*)(smem + 32768);     // 8 waves x 32 rows x 64 shorts = 32KB
    float* mbf = (float*)(smem + 65536);     // 8KB bias: 0 valid / -1e30 masked
    float* Os  = (float*)smem;               // epilogue [64][260] f32 (reuse)

    const int tid  = threadIdx.x;
    const int lane = tid & 63, wid = tid >> 6;      // wid 0..7
    const int l15  = lane & 15, quad = lane >> 4;

    const int blk  = blockIdx.x;             // 0..255
    const int head = blk & 31;               // same-head blocks share XCD
    const int qt   = blk >> 5;               // 0..7
    const int b    = head >> 4, h = head & 15;
    const int t0   = qt * 256;

    const short* QT = ws + QT_OFF + (long)head * 131072;   // [t][c]
    const char*  KB = (const char*)(ws + KF_OFF + (long)head * 131072);  // frag-major, bytes
    const char*  VB = (const char*)(ws + VF_OFF + (long)head * 131072);  // frag-major, bytes
    const long obase = ((long)b * 1024 + h * 64) * TSEQ;

    for (int i = tid; i < TSEQ; i += 512)
        mbf[i] = (mask[b * TSEQ + i] != 0) ? 0.0f : -1e30f;

    // stage tile 0 into buf0 (each wave copies 1KB of K and 1KB of V)
    GLOAD16(KB + wid * 1024 + lane * 16, smem + wid * 1024);
    GLOAD16(VB + wid * 1024 + lane * 16, smem + 8192 + wid * 1024);
    __syncthreads();   // drains vmcnt(0): tile 0 resident; mbf visible

    // Q frags: one-time segmented global loads
    bf16x8 qb[2][2];
    #pragma unroll
    for (int nt = 0; nt < 2; ++nt)
        #pragma unroll
        for (int hf = 0; hf < 2; ++hf)
            qb[nt][hf] = *(const bf16x8*)(QT +
                (long)(t0 + wid * 32 + nt * 16 + l15) * 64 + quad * 8 + hf * 32);
    bool qv[2];
    #pragma unroll
    for (int nt = 0; nt < 2; ++nt)
        qv[nt] = (mbf[t0 + wid * 32 + nt * 16 + l15] != 0.0f);

    float l_s[2] = {0.0f, 0.0f};
    f32x4 Oacc[2][4];
    #pragma unroll
    for (int mt = 0; mt < 2; ++mt)
        #pragma unroll
        for (int nc = 0; nc < 4; ++nc)
            #pragma unroll
            for (int r = 0; r < 4; ++r) Oacc[mt][nc][r] = 0.0f;

    short* Pw = Ps + wid * 2048;

    int cur = 0;
    for (int it = 0; it < 32; ++it) {
        // issue next-tile staging into the other buffer (hidden under compute)
        if (it != 31) {
            const long nb = (long)(it + 1) * 8192;
            GLOAD16(KB + nb + wid * 1024 + lane * 16,
                    smem + (cur ^ 1) * 16384 + wid * 1024);
            GLOAD16(VB + nb + wid * 1024 + lane * 16,
                    smem + (cur ^ 1) * 16384 + 8192 + wid * 1024);
        }
        const short* kb = (const short*)(smem + cur * 16384);
        const short* vb = (const short*)(smem + cur * 16384 + 8192);

        // K frags from LDS (conflict-free contiguous ds_read_b128)
        bf16x8 kc[8];
        #pragma unroll
        for (int f = 0; f < 8; ++f)
            kc[f] = *(const bf16x8*)(kb + f * 512 + lane * 8);

        // mask bias (MFMA C-init), broadcast LDS reads
        f32x4 bias[4];
        #pragma unroll
        for (int ns = 0; ns < 4; ++ns)
            bias[ns] = *(const f32x4*)&mbf[it * 64 + ns * 16 + quad * 4];

        // S^T = K Q^T + bias
        f32x4 Sacc[4][2];
        __builtin_amdgcn_s_setprio(1);
        #pragma unroll
        for (int ns = 0; ns < 4; ++ns)
            #pragma unroll
            for (int nt = 0; nt < 2; ++nt) {
                Sacc[ns][nt] = __builtin_amdgcn_mfma_f32_16x16x32_bf16(
                    kc[ns * 2 + 0], qb[nt][0], bias[ns], 0, 0, 0);
                Sacc[ns][nt] = __builtin_amdgcn_mfma_f32_16x16x32_bf16(
                    kc[ns * 2 + 1], qb[nt][1], Sacc[ns][nt], 0, 0, 0);
            }
        __builtin_amdgcn_s_setprio(0);

        // fixed-max softmax; P write with XOR-swizzled layout (<=2-way banks)
        #pragma unroll
        for (int nt = 0; nt < 2; ++nt) {
            const int row = nt * 16 + l15;
            const int sw  = (row & 7) ^ ((row & 8) >> 1);
            float ls = 0.0f;
            #pragma unroll
            for (int ns = 0; ns < 4; ++ns) {
                float pv[4];
                #pragma unroll
                for (int r = 0; r < 4; ++r) {
                    float e = EXPFN(Sacc[ns][nt][r]);
                    pv[r] = qv[nt] ? 1.0f : e;
                    ls += pv[r];
                }
                const int cbp = (ns * 2 + (quad >> 1)) ^ sw;
                uint2 pk;
                pk.x = pkbf(pv[0], pv[1]);
                pk.y = pkbf(pv[2], pv[3]);
                *(uint2*)&Pw[row * 64 + cbp * 8 + (quad & 1) * 4] = pk;
            }
            ls += __shfl_xor(ls, 16);
            ls += __shfl_xor(ls, 32);
            l_s[nt] += ls;
        }

        // P read (same swizzle) + V frags from LDS + O += P V^T
        bf16x8 pa[2][2];
        #pragma unroll
        for (int mt = 0; mt < 2; ++mt) {
            const int row = mt * 16 + l15;
            const int sw  = (row & 7) ^ ((row & 8) >> 1);
            #pragma unroll
            for (int hf = 0; hf < 2; ++hf)
                pa[mt][hf] = *(const bf16x8*)&Pw[row * 64 + ((quad + 4 * hf) ^ sw) * 8];
        }
        bf16x8 vf[8];
        #pragma unroll
        for (int f = 0; f < 8; ++f)
            vf[f] = *(const bf16x8*)(vb + f * 512 + lane * 8);

        __builtin_amdgcn_s_setprio(1);
        #pragma unroll
        for (int hf = 0; hf < 2; ++hf)
            #pragma unroll
            for (int nc = 0; nc < 4; ++nc)
                #pragma unroll
                for (int mt = 0; mt < 2; ++mt)
                    Oacc[mt][nc] = __builtin_amdgcn_mfma_f32_16x16x32_bf16(
                        pa[mt][hf], vf[nc * 2 + hf], Oacc[mt][nc], 0, 0, 0);
        __builtin_amdgcn_s_setprio(0);

        // barrier: next tile staged (vmcnt drain), all waves done with buf[cur]
        __syncthreads();
        cur ^= 1;
    }

    // epilogue: O/l -> Os [c][t] f32 -> coalesced float4 stores
    // (loop-end barrier already synced; smem fully dead, reuse as Os)
    float inv[2];
    #pragma unroll
    for (int nt = 0; nt < 2; ++nt) inv[nt] = 1.0f / l_s[nt];
    float iw[2][4];
    #pragma unroll
    for (int mt = 0; mt < 2; ++mt)
        #pragma unroll
        for (int r = 0; r < 4; ++r)
            iw[mt][r] = __shfl(inv[mt], 4 * quad + r);
    #pragma unroll
    for (int mt = 0; mt < 2; ++mt)
        #pragma unroll
        for (int nc = 0; nc < 4; ++nc) {
            float4 o;
            o.x = Oacc[mt][nc][0] * iw[mt][0];
            o.y = Oacc[mt][nc][1] * iw[mt][1];
            o.z = Oacc[mt][nc][2] * iw[mt][2];
            o.w = Oacc[mt][nc][3] * iw[mt][3];
            *(float4*)&Os[(nc * 16 + l15) * 260 + wid * 32 + mt * 16 + quad * 4] = o;
        }
    __syncthreads();
    #pragma unroll
    for (int ch = 0; ch < 8; ++ch) {
        int idx = tid + ch * 512;           // 0..4095
        int c = idx >> 6, tch = idx & 63;
        *(float4*)(out + obase + (long)c * TSEQ + t0 + tch * 4) =
            *(const float4*)&Os[c * 260 + tch * 4];
    }
}

extern "C" void kernel_launch(void* const* d_in, const int* in_sizes, int n_in,
                              void* d_out, int out_size, void* d_ws, size_t ws_size,
                              hipStream_t stream) {
    const float* qkv  = (const float*)d_in[0];
    const int*   mask = (const int*)d_in[1];
    float*       out  = (float*)d_out;
    short*       ws   = (short*)d_ws;       // needs 24 MiB
    prep_kernel<<<dim3(3072), dim3(256), 0, stream>>>(qkv, ws);
    attn_kernel<<<dim3(256), dim3(512), 0, stream>>>(ws, mask, out);
}

// Round 2
// 136.962 us; speedup vs baseline: 1.0814x; 1.0814x over previous
//
#include <hip/hip_runtime.h>
#include <float.h>

// QKV attention, qkv [2,3072,2048] f32, mask [2,1,2048] i32, out [2,1024,2048] f32.
// Prep: f32->bf16; Q -> [bh][t][c] (pre-scaled 1/8*log2e); K,V -> FRAG-MAJOR:
// per (head, s-tile, frag) a 64-lane x 16B contiguous block == one coalesced
// 1KB wave load that lands directly in MFMA A/B layout.
// Main: barrier-free flash loop. R2 restructure: fixed-max softmax makes the
// s-loop fully parallel (partial l/O over disjoint s just ADD), so waves split
// BOTH q (2 x 32 rows) and s (2 interleaved halves): 256-thr blocks, grid 1024
// -> 4 blocks/CU, 4 waves/SIMD (was 2) to cover the latency stalls that held
// R0/R1 at 2.9x the VALU floor. K/V direct from L1/L2 (R1 proved staging is
// not the bottleneck); no K prefetch dbuf (saves 32 VGPR, TLP hides latency).
// Pair-combine l/O through LDS in epilogue only.

typedef __attribute__((ext_vector_type(8))) short bf16x8;
typedef __attribute__((ext_vector_type(4))) float f32x4;

#define TSEQ 2048
#define QT_OFF 0L
#define KF_OFF 4194304L
#define VF_OFF 8388608L

#if __has_builtin(__builtin_amdgcn_exp2f)
#define EXPFN(x) __builtin_amdgcn_exp2f(x)
#define SM_SCALE (0.125f * 1.44269504088896f)
#else
#define EXPFN(x) __expf(x)
#define SM_SCALE 0.125f
#endif

__device__ inline short f2bf(float x) {
    union { float f; unsigned u; } un; un.f = x;
    unsigned r = un.u + 0x7fffu + ((un.u >> 16) & 1u);  // RNE
    return (short)(r >> 16);
}

// pack two nonneg floats to bf16 pair, round-half-up: 1 add each + 1 perm
__device__ inline unsigned pkbf(float a, float b) {
    unsigned au = __float_as_uint(a) + 0x8000u;
    unsigned bu = __float_as_uint(b) + 0x8000u;
    return __builtin_amdgcn_perm(bu, au, 0x07060302u);  // [a_hi16 | b_hi16<<16]
}

// ---------------- pre-pass: convert + reorder ----------------
__global__ __launch_bounds__(256) void prep_kernel(
    const float* __restrict__ qkv, short* __restrict__ ws)
{
    const int tid = threadIdx.x;
    const int job = blockIdx.x;
    if (job < 2048) {
        __shared__ float Ls[64 * 65];   // [c][t]
        const int which = job & 1;      // 0=Q 1=K
        const int rest  = job >> 1;
        const int bh = rest & 31, tt = rest >> 5;
        const int b = bh >> 4, h = bh & 15;
        const float* src = qkv + (long)b * 6291456 + ((long)(which * 1024 + h * 64)) * TSEQ + tt * 64;
        #pragma unroll
        for (int ch = 0; ch < 4; ++ch) {
            int idx = tid + ch * 256;
            int c = idx >> 4, tch = idx & 15;
            float4 v = *(const float4*)(src + (long)c * TSEQ + tch * 4);
            float* L = &Ls[c * 65 + tch * 4];
            L[0] = v.x; L[1] = v.y; L[2] = v.z; L[3] = v.w;
        }
        __syncthreads();
        if (which == 0) {
            // Q -> [t][c], scaled
            short* dst = ws + QT_OFF + ((long)bh * TSEQ + tt * 64) * 64;
            #pragma unroll
            for (int ch = 0; ch < 2; ++ch) {
                int idx = tid + ch * 256;
                int t = idx >> 3, cch = idx & 7;
                bf16x8 o;
                #pragma unroll
                for (int j = 0; j < 8; ++j)
                    o[j] = f2bf(Ls[(cch * 8 + j) * 65 + t] * SM_SCALE);
                *(bf16x8*)(dst + (long)t * 64 + cch * 8) = o;
            }
        } else {
            // K -> frag-major: unit (f=ns*2+hf, lane) = K[s=tt*64+ns*16+l15][c=hf*32+q*8+j]
            short* dst = ws + KF_OFF + (long)(bh * 32 + tt) * 4096;
            #pragma unroll
            for (int ch = 0; ch < 2; ++ch) {
                int u = tid + ch * 256;             // 0..511
                int f = u >> 6, lane = u & 63;
                int q = lane >> 4, l15 = lane & 15;
                int hf = f & 1, ns = f >> 1;
                bf16x8 o;
                #pragma unroll
                for (int j = 0; j < 8; ++j)
                    o[j] = f2bf(Ls[(hf * 32 + q * 8 + j) * 65 + ns * 16 + l15]);
                *(bf16x8*)(dst + f * 512 + lane * 8) = o;
            }
        }
    } else {
        // V -> frag-major: unit (f=nc*2+hf, lane) = V[c=nc*16+l15][s=it*64+hf*32+q*8+j]
        // u = tid + ch*256: f is wave-uniform per load -> each wave-instr touches
        // 16 rows x full lines instead of a 64-line scatter (R2 coalescing fix).
        const int v = job - 2048;               // 0..1023
        const int head = v >> 5, it = v & 31;
        const int b = head >> 4, h = head & 15;
        short* dst = ws + VF_OFF + (long)(head * 32 + it) * 4096;
        #pragma unroll
        for (int ch = 0; ch < 2; ++ch) {
            int u = tid + ch * 256;             // 0..511
            int f = u >> 6, lane = u & 63;
            int q = lane >> 4, l15 = lane & 15;
            int hf = f & 1, nc = f >> 1;
            const float* src = qkv + (long)b * 6291456
                + ((long)(2048 + h * 64 + nc * 16 + l15)) * TSEQ
                + it * 64 + hf * 32 + q * 8;
            float4 a  = *(const float4*)src;
            float4 c4 = *(const float4*)(src + 4);
            bf16x8 o;
            o[0] = f2bf(a.x);  o[1] = f2bf(a.y);  o[2] = f2bf(a.z);  o[3] = f2bf(a.w);
            o[4] = f2bf(c4.x); o[5] = f2bf(c4.y); o[6] = f2bf(c4.z); o[7] = f2bf(c4.w);
            *(bf16x8*)(dst + f * 512 + lane * 8) = o;
        }
    }
}

// ---------------- main attention (4 waves: 2q x 2s, barrier-free loop) ----------------
__global__ __launch_bounds__(256, 4) void attn_kernel(
    const short* __restrict__ wsp, const int* __restrict__ mask,
    float* __restrict__ out)
{
    __shared__ __align__(16) char smem[24576];
    short* Ps  = (short*)smem;               // 4 waves x 32 rows x 64 shorts = 16KB
    float* mbf = (float*)(smem + 16384);     // 8KB bias: 0 valid / -1e30 masked
    float* Os  = (float*)smem;               // epilogue [64][68] f32 = 17408B (reuse)
    float* Lc  = (float*)(smem + 20480);     // 128 floats l-combine (above Os end)

    const int tid  = threadIdx.x;
    const int lane = tid & 63, wid = tid >> 6;      // wid 0..3
    const int l15  = lane & 15, quad = lane >> 4;
    const int wq   = wid & 1,  wss  = wid >> 1;     // q-subtile / s-half

    const int blk  = blockIdx.x;             // 0..1023
    const int head = blk & 31;               // same-head blocks 32 apart -> same XCD
    const int qt   = blk >> 5;               // 0..31
    const int b    = head >> 4, h = head & 15;
    const int t0   = qt * 64;

    const short* QT = wsp + QT_OFF + (long)head * 131072;   // [t][c]
    const short* KF = wsp + KF_OFF + (long)head * 131072;   // frag-major
    const short* VF = wsp + VF_OFF + (long)head * 131072;   // frag-major
    const long obase = ((long)b * 1024 + h * 64) * TSEQ;

    for (int i = tid; i < TSEQ; i += 256)
        mbf[i] = (mask[b * TSEQ + i] != 0) ? 0.0f : -1e30f;
    __syncthreads();

    // Q frags: one-time segmented global loads (32 rows per wave)
    bf16x8 qb[2][2];
    #pragma unroll
    for (int nt = 0; nt < 2; ++nt)
        #pragma unroll
        for (int hf = 0; hf < 2; ++hf)
            qb[nt][hf] = *(const bf16x8*)(QT +
                (long)(t0 + wq * 32 + nt * 16 + l15) * 64 + quad * 8 + hf * 32);
    bool qv[2];
    #pragma unroll
    for (int nt = 0; nt < 2; ++nt)
        qv[nt] = (mbf[t0 + wq * 32 + nt * 16 + l15] != 0.0f);

    float l_s[2] = {0.0f, 0.0f};
    f32x4 Oacc[2][4];
    #pragma unroll
    for (int mt = 0; mt < 2; ++mt)
        #pragma unroll
        for (int nc = 0; nc < 4; ++nc)
            #pragma unroll
            for (int r = 0; r < 4; ++r) Oacc[mt][nc][r] = 0.0f;

    short* Pw = Ps + wid * 2048;
    const short* KL = KF + lane * 8;
    const short* VL = VF + lane * 8;

    // s-halves interleaved: wave wss does tiles wss, wss+2, ... (16 tiles)
    for (int i = 0; i < 16; ++i) {
        const int it = wss + i * 2;

        // K frags for this tile (8 coalesced 1KB wave loads, L1/L2-hit)
        const short* kp = KL + (long)it * 4096;
        bf16x8 kc[8];
        #pragma unroll
        for (int f = 0; f < 8; ++f)
            kc[f] = *(const bf16x8*)(kp + f * 512);

        // mask bias (MFMA C-init), broadcast LDS reads
        f32x4 bias[4];
        #pragma unroll
        for (int ns = 0; ns < 4; ++ns)
            bias[ns] = *(const f32x4*)&mbf[it * 64 + ns * 16 + quad * 4];

        // S^T = K Q^T + bias
        f32x4 Sacc[4][2];
        __builtin_amdgcn_s_setprio(1);
        #pragma unroll
        for (int ns = 0; ns < 4; ++ns)
            #pragma unroll
            for (int nt = 0; nt < 2; ++nt) {
                Sacc[ns][nt] = __builtin_amdgcn_mfma_f32_16x16x32_bf16(
                    kc[ns * 2 + 0], qb[nt][0], bias[ns], 0, 0, 0);
                Sacc[ns][nt] = __builtin_amdgcn_mfma_f32_16x16x32_bf16(
                    kc[ns * 2 + 1], qb[nt][1], Sacc[ns][nt], 0, 0, 0);
            }
        __builtin_amdgcn_s_setprio(0);

        // fixed-max softmax; P write with XOR-swizzled layout (<=2-way banks)
        #pragma unroll
        for (int nt = 0; nt < 2; ++nt) {
            const int row = nt * 16 + l15;
            const int sw  = (row & 7) ^ ((row & 8) >> 1);
            float ls = 0.0f;
            #pragma unroll
            for (int ns = 0; ns < 4; ++ns) {
                float pv[4];
                #pragma unroll
                for (int r = 0; r < 4; ++r) {
                    float e = EXPFN(Sacc[ns][nt][r]);
                    pv[r] = qv[nt] ? 1.0f : e;
                    ls += pv[r];
                }
                const int cbp = (ns * 2 + (quad >> 1)) ^ sw;
                uint2 pk;
                pk.x = pkbf(pv[0], pv[1]);
                pk.y = pkbf(pv[2], pv[3]);
                *(uint2*)&Pw[row * 64 + cbp * 8 + (quad & 1) * 4] = pk;
            }
            ls += __shfl_xor(ls, 16);
            ls += __shfl_xor(ls, 32);
            l_s[nt] += ls;
        }

        // V frags (issued between P write and P read; TLP hides latency)
        const short* vp = VL + (long)it * 4096;
        bf16x8 vf[8];
        #pragma unroll
        for (int f = 0; f < 8; ++f)
            vf[f] = *(const bf16x8*)(vp + f * 512);

        // P read (same swizzle) + O += P V^T
        bf16x8 pa[2][2];
        #pragma unroll
        for (int mt = 0; mt < 2; ++mt) {
            const int row = mt * 16 + l15;
            const int sw  = (row & 7) ^ ((row & 8) >> 1);
            #pragma unroll
            for (int hf = 0; hf < 2; ++hf)
                pa[mt][hf] = *(const bf16x8*)&Pw[row * 64 + ((quad + 4 * hf) ^ sw) * 8];
        }
        __builtin_amdgcn_s_setprio(1);
        #pragma unroll
        for (int hf = 0; hf < 2; ++hf)
            #pragma unroll
            for (int nc = 0; nc < 4; ++nc)
                #pragma unroll
                for (int mt = 0; mt < 2; ++mt)
                    Oacc[mt][nc] = __builtin_amdgcn_mfma_f32_16x16x32_bf16(
                        pa[mt][hf], vf[nc * 2 + hf], Oacc[mt][nc], 0, 0, 0);
        __builtin_amdgcn_s_setprio(0);
    }

    // ---- epilogue: combine s-halves, scale, store ----
    __syncthreads();                         // all waves done: Ps/mbf dead
    if (quad == 0) {
        Lc[wid * 32 + l15]      = l_s[0];
        Lc[wid * 32 + 16 + l15] = l_s[1];
    }
    __syncthreads();
    float inv[2];
    #pragma unroll
    for (int nt = 0; nt < 2; ++nt)
        inv[nt] = 1.0f / (l_s[nt] + Lc[(wid ^ 2) * 32 + nt * 16 + l15]);
    float iw[2][4];
    #pragma unroll
    for (int mt = 0; mt < 2; ++mt)
        #pragma unroll
        for (int r = 0; r < 4; ++r)
            iw[mt][r] = __shfl(inv[mt], 4 * quad + r);

    if (wss == 0) {
        #pragma unroll
        for (int mt = 0; mt < 2; ++mt)
            #pragma unroll
            for (int nc = 0; nc < 4; ++nc) {
                float4 o;
                o.x = Oacc[mt][nc][0] * iw[mt][0];
                o.y = Oacc[mt][nc][1] * iw[mt][1];
                o.z = Oacc[mt][nc][2] * iw[mt][2];
                o.w = Oacc[mt][nc][3] * iw[mt][3];
                *(float4*)&Os[(nc * 16 + l15) * 68 + wq * 32 + mt * 16 + quad * 4] = o;
            }
    }
    __syncthreads();
    if (wss == 1) {
        #pragma unroll
        for (int mt = 0; mt < 2; ++mt)
            #pragma unroll
            for (int nc = 0; nc < 4; ++nc) {
                float* p = &Os[(nc * 16 + l15) * 68 + wq * 32 + mt * 16 + quad * 4];
                p[0] += Oacc[mt][nc][0] * iw[mt][0];
                p[1] += Oacc[mt][nc][1] * iw[mt][1];
                p[2] += Oacc[mt][nc][2] * iw[mt][2];
                p[3] += Oacc[mt][nc][3] * iw[mt][3];
            }
    }
    __syncthreads();
    #pragma unroll
    for (int ch = 0; ch < 4; ++ch) {
        int idx = tid + ch * 256;           // 0..1023
        int c = idx >> 4, tch = idx & 15;
        *(float4*)(out + obase + (long)c * TSEQ + t0 + tch * 4) =
            *(const float4*)&Os[c * 68 + tch * 4];
    }
}

extern "C" void kernel_launch(void* const* d_in, const int* in_sizes, int n_in,
                              void* d_out, int out_size, void* d_ws, size_t ws_size,
                              hipStream_t stream) {
    const float* qkv  = (const float*)d_in[0];
    const int*   mask = (const int*)d_in[1];
    float*       out  = (float*)d_out;
    short*       ws   = (short*)d_ws;       // needs 24 MiB
    prep_kernel<<<dim3(3072), dim3(256), 0, stream>>>(qkv, ws);
    attn_kernel<<<dim3(1024), dim3(256), 0, stream>>>(ws, mask, out);
}